// Round 3
// baseline (260.397 us; speedup 1.0000x reference)
//
#include <hip/hip_runtime.h>

// Circuit_67473936220746, round 3: single fused kernel (both passes in LDS).
//
// State viewed per high-index h (bits 14-22, 512 values) as a 128 KB tile
// T[ch][b][a] (b = bits 7-13, a = bits 0-6).
//   Pass A: out1[ch'][k_a][b] = sum_{ch,a} WA[ch'*128+k_a][ch*128+a] T[ch][b][a]
//           (WA = W2*W1*W0 composed in fp32 on device)
//   Pass B: out2[ch''][k_b][k_a] = sum_{ch',b} WB[ch''*128+k_b][ch'*128+b] out1[ch'][k_a][b]
//           (WB = W3)
// out1 lives in LDS (transposed layout [kp=ch'*128+k_a][b], stride 132 fp32).
// Precision: 3-term bf16 split per pass (Xh*Wh + Xl*Wh + Xh*Wl), fp32 acc.
//
// MFMA 16x16x32 bf16 layouts (HW-verified):
//   A: m = lane&15, k = (lane>>4)*8 + j (16B contiguous)
//   B: n = lane&15, k = (lane>>4)*8 + j
//   C/D: col(n) = lane&15, row(m) = (lane>>4)*4 + reg

typedef __attribute__((ext_vector_type(8))) short bf16x8;
typedef __attribute__((ext_vector_type(4))) float f32x4;

static constexpr int NSTATE = 1 << 23;
static constexpr int MSTR   = 132;     // mid LDS row stride (fp32): 132%32=4 -> 2-way banks (free)

__device__ inline void bf16_split(float x, unsigned short& h, unsigned short& l) {
    union { float f; unsigned int u; } a; a.f = x;
    unsigned int r = (a.u + 0x7FFFu + ((a.u >> 16) & 1u)) >> 16;   // RNE
    h = (unsigned short)r;
    union { unsigned int u; float f; } b; b.u = r << 16;
    union { float f; unsigned int u; } c; c.f = x - b.f;
    unsigned int r2 = (c.u + 0x7FFFu + ((c.u >> 16) & 1u)) >> 16;
    l = (unsigned short)r2;
}

__device__ inline void split8(const float* xv, bf16x8& hv, bf16x8& lv) {
    #pragma unroll
    for (int i = 0; i < 8; ++i) {
        unsigned short hh, ll;
        bf16_split(xv[i], hh, ll);
        hv[i] = (short)hh; lv[i] = (short)ll;
    }
}

// ---- prep: signed 256x256 W_g from U[g], g=0..2 (fp32) ----
__global__ void assemble_W(const float* __restrict__ U, float* __restrict__ W) {
    const int g  = blockIdx.y;
    const int kp = blockIdx.x, ap = threadIdx.x;
    const int co = kp >> 7, ci = ap >> 7;
    const int c  = (co == ci) ? 1 : 0;
    const float sgn = (co & ci) ? -1.f : 1.f;
    W[(size_t)g * 65536 + kp * 256 + ap] =
        sgn * U[(size_t)g * 32768 + c * 16384 + (kp & 127) * 128 + (ap & 127)];
}

// ---- prep: C = A*B 256^3 fp32, tiled (8 rows/block, A in LDS) ----
__global__ __launch_bounds__(256)
void matmul256(const float* __restrict__ A, const float* __restrict__ B,
               float* __restrict__ C) {
    __shared__ float As[8][256];
    const int t = threadIdx.x, i0 = blockIdx.x * 8;
    #pragma unroll
    for (int r = 0; r < 8; ++r) As[r][t] = A[(i0 + r) * 256 + t];
    __syncthreads();
    float acc[8] = {};
    #pragma unroll 8
    for (int k = 0; k < 256; ++k) {
        const float bv = B[k * 256 + t];
        #pragma unroll
        for (int r = 0; r < 8; ++r) acc[r] = fmaf(As[r][k], bv, acc[r]);
    }
    #pragma unroll
    for (int r = 0; r < 8; ++r) C[(i0 + r) * 256 + t] = acc[r];
}

// ---- prep: split fp32 -> bf16 hi/lo ----
__global__ void split_bf16(const float* __restrict__ Wf, unsigned short* __restrict__ Wh,
                           unsigned short* __restrict__ Wl) {
    const int idx = blockIdx.x * 256 + threadIdx.x;
    bf16_split(Wf[idx], Wh[idx], Wl[idx]);
}

// ---- prep: W3 assembled+split directly from U ----
__global__ void split_WB(const float* __restrict__ U, unsigned short* __restrict__ Wh,
                         unsigned short* __restrict__ Wl) {
    const int kp = blockIdx.x, ap = threadIdx.x;
    const int co = kp >> 7, ci = ap >> 7;
    const int c  = (co == ci) ? 1 : 0;
    const float sgn = (co & ci) ? -1.f : 1.f;
    const float v = sgn * U[(size_t)3 * 32768 + c * 16384 + (kp & 127) * 128 + (ap & 127)];
    unsigned short hh, ll;
    bf16_split(v, hh, ll);
    Wh[kp * 256 + ap] = hh; Wl[kp * 256 + ap] = ll;
}

// ---- fused main kernel: 512 blocks (one per h), 512 threads (8 waves) ----
// wave w: m-group mg=w&3 (rows [mg*32,+32), 2 m-tiles), n-group ng=w>>2 (cols [ng*128,+128), 8 n-tiles)
__global__ __launch_bounds__(512, 2)
void fused_pass(const float* __restrict__ src, float* __restrict__ dst,
                const unsigned short* __restrict__ WAh, const unsigned short* __restrict__ WAl,
                const unsigned short* __restrict__ WBh, const unsigned short* __restrict__ WBl)
{
    __shared__ float MID[256 * MSTR];              // 135168 B

    const int t    = threadIdx.x;
    const int lane = t & 63;
    const int w    = t >> 6;
    const int mg   = w & 3, ng = w >> 2;
    const int m    = lane & 15, kg = lane >> 4;
    const int quad = lane >> 4, col = lane & 15;
    const size_t hbase = (size_t)blockIdx.x * 16384;

    bf16x8 AH[2][8], AL[2][8];                     // 128 VGPRs: full-K A-frags

    // ================= PASS A =================
    // A-frags straight from global: A[m=b][k=(ch,a)]
    #pragma unroll
    for (int mt = 0; mt < 2; ++mt) {
        const int b = mg * 32 + mt * 16 + m;
        #pragma unroll
        for (int ks = 0; ks < 8; ++ks) {
            const int ch = ks >> 2;
            const int a  = (ks & 3) * 32 + kg * 8;
            const float* p = src + (size_t)ch * NSTATE + hbase + (size_t)b * 128 + a;
            float xv[8];
            *(float4*)&xv[0] = *(const float4*)p;
            *(float4*)&xv[4] = *(const float4*)(p + 4);
            split8(xv, AH[mt][ks], AL[mt][ks]);
        }
    }
    // nt loop over this wave's 8 n-tiles
    #pragma unroll 2
    for (int j = 0; j < 8; ++j) {
        const int kp = (ng * 8 + j) * 16 + col;    // W row for this lane's B-frags / C col
        f32x4 acc0 = (f32x4)0.f, acc1 = (f32x4)0.f;
        #pragma unroll
        for (int ks = 0; ks < 8; ++ks) {
            const int ap = ks * 32 + kg * 8;
            bf16x8 bh = *(const bf16x8*)(WAh + kp * 256 + ap);
            bf16x8 bl = *(const bf16x8*)(WAl + kp * 256 + ap);
            acc0 = __builtin_amdgcn_mfma_f32_16x16x32_bf16(AH[0][ks], bh, acc0, 0, 0, 0);
            acc0 = __builtin_amdgcn_mfma_f32_16x16x32_bf16(AL[0][ks], bh, acc0, 0, 0, 0);
            acc0 = __builtin_amdgcn_mfma_f32_16x16x32_bf16(AH[0][ks], bl, acc0, 0, 0, 0);
            acc1 = __builtin_amdgcn_mfma_f32_16x16x32_bf16(AH[1][ks], bh, acc1, 0, 0, 0);
            acc1 = __builtin_amdgcn_mfma_f32_16x16x32_bf16(AL[1][ks], bh, acc1, 0, 0, 0);
            acc1 = __builtin_amdgcn_mfma_f32_16x16x32_bf16(AH[1][ks], bl, acc1, 0, 0, 0);
        }
        // write mid[kp][b], b = mg*32 + mt*16 + quad*4 + r  (float4)
        *(f32x4*)&MID[kp * MSTR + mg * 32 + 0 * 16 + quad * 4] = acc0;
        *(f32x4*)&MID[kp * MSTR + mg * 32 + 1 * 16 + quad * 4] = acc1;
    }
    __syncthreads();

    // ================= PASS B =================
    // A-frags from LDS: A[m=k_a][k=(ch',b)] = MID[(ch'*128+k_a)*MSTR + b]
    #pragma unroll
    for (int mt = 0; mt < 2; ++mt) {
        const int ka = mg * 32 + mt * 16 + m;
        #pragma unroll
        for (int ks = 0; ks < 8; ++ks) {
            const int chp = ks >> 2;
            const int b   = (ks & 3) * 32 + kg * 8;
            const float* p = &MID[(chp * 128 + ka) * MSTR + b];
            float xv[8];
            *(float4*)&xv[0] = *(const float4*)p;
            *(float4*)&xv[4] = *(const float4*)(p + 4);
            split8(xv, AH[mt][ks], AL[mt][ks]);
        }
    }
    #pragma unroll 2
    for (int j = 0; j < 8; ++j) {
        const int kp2 = (ng * 8 + j) * 16 + col;
        f32x4 acc0 = (f32x4)0.f, acc1 = (f32x4)0.f;
        #pragma unroll
        for (int ks = 0; ks < 8; ++ks) {
            const int ap = ks * 32 + kg * 8;
            bf16x8 bh = *(const bf16x8*)(WBh + kp2 * 256 + ap);
            bf16x8 bl = *(const bf16x8*)(WBl + kp2 * 256 + ap);
            acc0 = __builtin_amdgcn_mfma_f32_16x16x32_bf16(AH[0][ks], bh, acc0, 0, 0, 0);
            acc0 = __builtin_amdgcn_mfma_f32_16x16x32_bf16(AL[0][ks], bh, acc0, 0, 0, 0);
            acc0 = __builtin_amdgcn_mfma_f32_16x16x32_bf16(AH[0][ks], bl, acc0, 0, 0, 0);
            acc1 = __builtin_amdgcn_mfma_f32_16x16x32_bf16(AH[1][ks], bh, acc1, 0, 0, 0);
            acc1 = __builtin_amdgcn_mfma_f32_16x16x32_bf16(AL[1][ks], bh, acc1, 0, 0, 0);
            acc1 = __builtin_amdgcn_mfma_f32_16x16x32_bf16(AH[1][ks], bl, acc1, 0, 0, 0);
        }
        // out2[ch''][k_b][k_a]: k_a = mg*32 + mt*16 + quad*4 + r (float4 store)
        const int chpp = kp2 >> 7, kb = kp2 & 127;
        float* o = dst + (size_t)chpp * NSTATE + hbase + (size_t)kb * 128;
        *(float4*)(o + mg * 32 + 0 * 16 + quad * 4) = *(float4*)&acc0;
        *(float4*)(o + mg * 32 + 1 * 16 + quad * 4) = *(float4*)&acc1;
    }
}

extern "C" void kernel_launch(void* const* d_in, const int* in_sizes, int n_in,
                              void* d_out, int out_size, void* d_ws, size_t ws_size,
                              hipStream_t stream) {
    const float* state = (const float*)d_in[0];   // (2, 2^23)
    const float* U     = (const float*)d_in[1];   // (4, 2, 128, 128)
    float* out = (float*)d_out;

    // ws: W0,W1,W2 fp32 | T | WA | WAh WAl WBh WBl (bf16)
    float* W0 = (float*)d_ws;
    float* T  = W0 + 3 * 65536;
    float* WA = W0 + 4 * 65536;
    unsigned short* WAh = (unsigned short*)(W0 + 5 * 65536);
    unsigned short* WAl = WAh + 65536;
    unsigned short* WBh = WAh + 2 * 65536;
    unsigned short* WBl = WAh + 3 * 65536;

    assemble_W<<<dim3(256, 3), 256, 0, stream>>>(U, W0);
    matmul256<<<32, 256, 0, stream>>>(W0 + 65536, W0, T);        // T  = W1*W0
    matmul256<<<32, 256, 0, stream>>>(W0 + 2 * 65536, T, WA);    // WA = W2*T
    split_bf16<<<256, 256, 0, stream>>>(WA, WAh, WAl);
    split_WB<<<256, 256, 0, stream>>>(U, WBh, WBl);

    fused_pass<<<512, 512, 0, stream>>>(state, out, WAh, WAl, WBh, WBl);
}

// Round 4
// 255.496 us; speedup vs baseline: 1.0192x; 1.0192x over previous
//
#include <hip/hip_runtime.h>

// Circuit_67473936220746, round 4: fused both-pass kernel, 16-wave blocks,
// split-once LDS staging (bf16 hi/lo), pre-split MID, parallel prep.
//
// Per high-index h (bits 14-22, 512 values) the sub-tensor T[ch][b][a]
// (b = bits 7-13, a = bits 0-6) is 128 KB:
//   Pass A: mid[kp=ch'*128+ka][b] = sum_{ch,a} WA[kp][ch*128+a] T[ch][b][a]
//   Pass B: out[ch''][kb][ka]     = sum_{ch',b} WB[ch''*128+kb][ch'*128+b] mid[ch'*128+ka][b]
// WA = W2*W1*W0, WB = W3, Wg = [[Ui,Ur],[Ur,-Ui]] (256x256, fp32 composition).
// Precision: 3-term bf16 split per pass (Xh*Wh + Xl*Wh + Xh*Wl), fp32 acc.
//
// MFMA 16x16x32 bf16 (HW-verified layouts):
//   A: m = lane&15, k = (lane>>4)*8 + j   (16B contiguous per lane)
//   B: n = lane&15, k = (lane>>4)*8 + j
//   C/D: col(n) = lane&15, row(m) = (lane>>4)*4 + reg

typedef __attribute__((ext_vector_type(8))) short bf16x8;
typedef __attribute__((ext_vector_type(4))) short bf16x4;
typedef __attribute__((ext_vector_type(4))) float f32x4;

static constexpr int NSTATE = 1 << 23;
static constexpr int STR    = 136;   // LDS row stride (bf16): 68 dwords = 4 mod 32 -> 2-way (free), 16B align

// cheap truncation split: x ~= bf16(h) + bf16(l), err ~2^-16 rel
__device__ inline void tsplit(float x, unsigned short& h, unsigned short& l) {
    unsigned int u = __float_as_uint(x);
    h = (unsigned short)(u >> 16);
    float hf = __uint_as_float(u & 0xFFFF0000u);
    l = (unsigned short)(__float_as_uint(x - hf) >> 16);
}

// RNE split for weights (prep only)
__device__ inline void bf16_split(float x, unsigned short& h, unsigned short& l) {
    union { float f; unsigned int u; } a; a.f = x;
    unsigned int r = (a.u + 0x7FFFu + ((a.u >> 16) & 1u)) >> 16;
    h = (unsigned short)r;
    union { unsigned int u; float f; } b; b.u = r << 16;
    union { float f; unsigned int u; } c; c.f = x - b.f;
    l = (unsigned short)((c.u + 0x7FFFu + ((c.u >> 16) & 1u)) >> 16);
}

// ---- prep: signed 256x256 W_g from U[g], g=0..2 ----
__global__ void assemble_W(const float* __restrict__ U, float* __restrict__ W) {
    const int g  = blockIdx.y;
    const int kp = blockIdx.x, ap = threadIdx.x;
    const int co = kp >> 7, ci = ap >> 7;
    const int c  = (co == ci) ? 1 : 0;
    const float sgn = (co & ci) ? -1.f : 1.f;
    W[(size_t)g * 65536 + kp * 256 + ap] =
        sgn * U[(size_t)g * 32768 + c * 16384 + (kp & 127) * 128 + (ap & 127)];
}

// ---- prep: C = A*B 256^3 fp32, one row per block (256 blocks, coalesced B) ----
__global__ __launch_bounds__(256)
void matmul256(const float* __restrict__ A, const float* __restrict__ B,
               float* __restrict__ C) {
    __shared__ float Arow[256];
    const int i = blockIdx.x, t = threadIdx.x;
    Arow[t] = A[i * 256 + t];
    __syncthreads();
    float s = 0.f;
    #pragma unroll 8
    for (int k = 0; k < 256; ++k) s = fmaf(Arow[k], B[k * 256 + t], s);
    C[i * 256 + t] = s;
}

// ---- prep: split fp32 -> bf16 hi/lo ----
__global__ void split_bf16k(const float* __restrict__ Wf, unsigned short* __restrict__ Wh,
                            unsigned short* __restrict__ Wl) {
    const int idx = blockIdx.x * 256 + threadIdx.x;
    unsigned short h, l;
    bf16_split(Wf[idx], h, l);
    Wh[idx] = h; Wl[idx] = l;
}

// ---- prep: W3 assembled+split directly from U ----
__global__ void split_WB(const float* __restrict__ U, unsigned short* __restrict__ Wh,
                         unsigned short* __restrict__ Wl) {
    const int kp = blockIdx.x, ap = threadIdx.x;
    const int co = kp >> 7, ci = ap >> 7;
    const int c  = (co == ci) ? 1 : 0;
    const float sgn = (co & ci) ? -1.f : 1.f;
    const float v = sgn * U[(size_t)3 * 32768 + c * 16384 + (kp & 127) * 128 + (ap & 127)];
    unsigned short h, l;
    bf16_split(v, h, l);
    Wh[kp * 256 + ap] = h; Wl[kp * 256 + ap] = l;
}

// ---- fused main: 512 blocks x 1024 threads (16 waves), 1 block/CU ----
__global__ __launch_bounds__(1024, 4)
void fused_pass(const float* __restrict__ src, float* __restrict__ dst,
                const unsigned short* __restrict__ WAh, const unsigned short* __restrict__ WAl,
                const unsigned short* __restrict__ WBh, const unsigned short* __restrict__ WBl)
{
    __shared__ unsigned short Xh[256 * STR];   // 69632 B  (reused as MID-hi)
    __shared__ unsigned short Xl[256 * STR];   // 69632 B  (reused as MID-lo)

    const int t    = threadIdx.x;
    const int lane = t & 63;
    const int w    = t >> 6;            // 0..15
    const int mg   = w & 3;             // m-rows [mg*32, +32): 2 m-tiles
    const int ng   = w >> 2;            // n-cols [ng*64, +64): 4 n-tiles
    const int col  = lane & 15;
    const int quad = lane >> 4;
    const size_t hbase = (size_t)blockIdx.x * 16384;

    // ---- stage + split state tile into LDS (split ONCE) ----
    #pragma unroll
    for (int i = 0; i < 8; ++i) {
        const int e  = i * 4096 + t * 4;            // fp32 element index in tile
        const int ch = e >> 14;
        const int row = (e >> 7) & 255;             // within-channel row index (b) + ch folding below
        const int a  = e & 127;
        const float4 v = *(const float4*)(src + (size_t)ch * NSTATE + hbase + (e & 16383));
        unsigned short h0,l0,h1,l1,h2,l2,h3,l3;
        tsplit(v.x, h0, l0); tsplit(v.y, h1, l1);
        tsplit(v.z, h2, l2); tsplit(v.w, h3, l3);
        const int off = (ch * 128 + ((e >> 7) & 127)) * STR + a;
        (void)row;
        bf16x4 hv = { (short)h0, (short)h1, (short)h2, (short)h3 };
        bf16x4 lv = { (short)l0, (short)l1, (short)l2, (short)l3 };
        *(bf16x4*)&Xh[off] = hv;
        *(bf16x4*)&Xl[off] = lv;
    }
    __syncthreads();

    // ================= PASS A =================
    f32x4 acc[2][4];
    #pragma unroll
    for (int mt = 0; mt < 2; ++mt)
        #pragma unroll
        for (int nt = 0; nt < 4; ++nt) acc[mt][nt] = (f32x4)0.f;

    #pragma unroll 2
    for (int ks = 0; ks < 8; ++ks) {
        const int ch = ks >> 2;
        const int a  = (ks & 3) * 32 + quad * 8;
        bf16x8 ah[2], al[2];
        #pragma unroll
        for (int mt = 0; mt < 2; ++mt) {
            const int b = mg * 32 + mt * 16 + col;
            const int off = (ch * 128 + b) * STR + a;
            ah[mt] = *(const bf16x8*)&Xh[off];
            al[mt] = *(const bf16x8*)&Xl[off];
        }
        const int kk = ks * 32 + quad * 8;
        #pragma unroll
        for (int nt = 0; nt < 4; ++nt) {
            const int kp = ng * 64 + nt * 16 + col;
            bf16x8 bh = *(const bf16x8*)(WAh + kp * 256 + kk);
            bf16x8 bl = *(const bf16x8*)(WAl + kp * 256 + kk);
            #pragma unroll
            for (int mt = 0; mt < 2; ++mt) {
                acc[mt][nt] = __builtin_amdgcn_mfma_f32_16x16x32_bf16(ah[mt], bh, acc[mt][nt], 0, 0, 0);
                acc[mt][nt] = __builtin_amdgcn_mfma_f32_16x16x32_bf16(al[mt], bh, acc[mt][nt], 0, 0, 0);
                acc[mt][nt] = __builtin_amdgcn_mfma_f32_16x16x32_bf16(ah[mt], bl, acc[mt][nt], 0, 0, 0);
            }
        }
    }
    __syncthreads();   // all X reads complete before overwrite

    // ---- write MID pre-split into the same LDS buffers ----
    #pragma unroll
    for (int mt = 0; mt < 2; ++mt) {
        #pragma unroll
        for (int nt = 0; nt < 4; ++nt) {
            const int kp   = ng * 64 + nt * 16 + col;           // mid row
            const int bcol = mg * 32 + mt * 16 + quad * 4;      // mid col (4 consecutive)
            unsigned short h0,l0,h1,l1,h2,l2,h3,l3;
            tsplit(acc[mt][nt][0], h0, l0); tsplit(acc[mt][nt][1], h1, l1);
            tsplit(acc[mt][nt][2], h2, l2); tsplit(acc[mt][nt][3], h3, l3);
            bf16x4 hv = { (short)h0, (short)h1, (short)h2, (short)h3 };
            bf16x4 lv = { (short)l0, (short)l1, (short)l2, (short)l3 };
            *(bf16x4*)&Xh[kp * STR + bcol] = hv;
            *(bf16x4*)&Xl[kp * STR + bcol] = lv;
        }
    }
    __syncthreads();

    // ================= PASS B =================
    f32x4 acc2[2][4];
    #pragma unroll
    for (int mt = 0; mt < 2; ++mt)
        #pragma unroll
        for (int nt = 0; nt < 4; ++nt) acc2[mt][nt] = (f32x4)0.f;

    #pragma unroll 2
    for (int ks = 0; ks < 8; ++ks) {
        const int chp = ks >> 2;
        const int b   = (ks & 3) * 32 + quad * 8;
        bf16x8 ah[2], al[2];
        #pragma unroll
        for (int mt = 0; mt < 2; ++mt) {
            const int ka  = mg * 32 + mt * 16 + col;
            const int off = (chp * 128 + ka) * STR + b;
            ah[mt] = *(const bf16x8*)&Xh[off];
            al[mt] = *(const bf16x8*)&Xl[off];
        }
        const int kk = ks * 32 + quad * 8;
        #pragma unroll
        for (int nt = 0; nt < 4; ++nt) {
            const int kp2 = ng * 64 + nt * 16 + col;
            bf16x8 bh = *(const bf16x8*)(WBh + kp2 * 256 + kk);
            bf16x8 bl = *(const bf16x8*)(WBl + kp2 * 256 + kk);
            #pragma unroll
            for (int mt = 0; mt < 2; ++mt) {
                acc2[mt][nt] = __builtin_amdgcn_mfma_f32_16x16x32_bf16(ah[mt], bh, acc2[mt][nt], 0, 0, 0);
                acc2[mt][nt] = __builtin_amdgcn_mfma_f32_16x16x32_bf16(al[mt], bh, acc2[mt][nt], 0, 0, 0);
                acc2[mt][nt] = __builtin_amdgcn_mfma_f32_16x16x32_bf16(ah[mt], bl, acc2[mt][nt], 0, 0, 0);
            }
        }
    }

    // ---- epilogue: out[ch''][kb][ka], coalesced float4 along ka ----
    #pragma unroll
    for (int nt = 0; nt < 4; ++nt) {
        const int kp2  = ng * 64 + nt * 16 + col;
        const int chpp = kp2 >> 7, kb = kp2 & 127;
        float* o = dst + (size_t)chpp * NSTATE + hbase + (size_t)kb * 128;
        #pragma unroll
        for (int mt = 0; mt < 2; ++mt) {
            const int ka = mg * 32 + mt * 16 + quad * 4;
            *(float4*)(o + ka) = *(float4*)&acc2[mt][nt];
        }
    }
}

extern "C" void kernel_launch(void* const* d_in, const int* in_sizes, int n_in,
                              void* d_out, int out_size, void* d_ws, size_t ws_size,
                              hipStream_t stream) {
    const float* state = (const float*)d_in[0];   // (2, 2^23)
    const float* U     = (const float*)d_in[1];   // (4, 2, 128, 128)
    float* out = (float*)d_out;

    // ws: W0,W1,W2 fp32 | T | WA | WAh WAl WBh WBl (bf16)
    float* W0 = (float*)d_ws;
    float* T  = W0 + 3 * 65536;
    float* WA = W0 + 4 * 65536;
    unsigned short* WAh = (unsigned short*)(W0 + 5 * 65536);
    unsigned short* WAl = WAh + 65536;
    unsigned short* WBh = WAh + 2 * 65536;
    unsigned short* WBl = WAh + 3 * 65536;

    assemble_W<<<dim3(256, 3), 256, 0, stream>>>(U, W0);
    matmul256<<<256, 256, 0, stream>>>(W0 + 65536, W0, T);        // T  = W1*W0
    matmul256<<<256, 256, 0, stream>>>(W0 + 2 * 65536, T, WA);    // WA = W2*T
    split_bf16k<<<256, 256, 0, stream>>>(WA, WAh, WAl);
    split_WB<<<256, 256, 0, stream>>>(U, WBh, WBl);

    fused_pass<<<512, 1024, 0, stream>>>(state, out, WAh, WAl, WBh, WBl);
}

// Round 5
// 210.483 us; speedup vs baseline: 1.2371x; 1.2139x over previous
//
#include <hip/hip_runtime.h>

// Circuit_67473936220746, round 5: fused two-pass kernel, block = (h, ka-half),
// MID-only LDS in frag-linear layout (64 KB -> 2 blocks/CU), one barrier,
// pre-tiled frag-linear W, 3 prep launches.
//
// State per high-index h (bits 14-22): T[ch][b][a] (b = bits 7-13, a = bits 0-6).
//   Pass A: mid[kp=ch'*128+ka][b] = sum_{ch,a} WA[kp][ch*128+a] * T[ch][b][a]
//   Pass B: out[ch''][kb][ka]     = sum_{ch',b} WB[ch''*128+kb][ch'*128+b] * mid[ch'*128+ka][b]
// WA = W2*W1*W0 (fp32 on device), WB = W3, Wg = [[Ui,Ur],[Ur,-Ui]].
// Block handles ka in [ka0, ka0+64): pass A computes only those kp columns
// (all b), pass B is then block-local. 3-term bf16 split both passes.
//
// MFMA 16x16x32 bf16 layouts (HW-verified):
//   A: m = lane&15, k = (lane>>4)*8 + j (16B/lane contiguous)
//   B: n = lane&15, k = (lane>>4)*8 + j
//   C/D: col(n) = lane&15, row(m) = (lane>>4)*4 + reg
//
// Frag-linear W / MID storage: frag(tile,ks) = 64 slots x 8 shorts; lane reads
// 16 B at frag*1024 + lane*16 (conflict-free-minimum b128).

typedef __attribute__((ext_vector_type(8))) short bf16x8;
typedef __attribute__((ext_vector_type(4))) short bf16x4;
typedef __attribute__((ext_vector_type(4))) float f32x4;

static constexpr int NSTATE = 1 << 23;

// truncation split: x ~= bf16(h) + bf16(l), rel err ~2^-16
__device__ inline void tsplit(float x, unsigned short& h, unsigned short& l) {
    unsigned int u = __float_as_uint(x);
    h = (unsigned short)(u >> 16);
    float hf = __uint_as_float(u & 0xFFFF0000u);
    l = (unsigned short)(__float_as_uint(x - hf) >> 16);
}

// RNE split (weights, prep only)
__device__ inline void rsplit(float x, unsigned short& h, unsigned short& l) {
    unsigned int u = __float_as_uint(x);
    unsigned int r = (u + 0x7FFFu + ((u >> 16) & 1u)) >> 16;
    h = (unsigned short)r;
    float hf = __uint_as_float(r << 16);
    unsigned int u2 = __float_as_uint(x - hf);
    l = (unsigned short)((u2 + 0x7FFFu + ((u2 >> 16) & 1u)) >> 16);
}

__device__ inline void split8(const float* xv, bf16x8& hv, bf16x8& lv) {
    #pragma unroll
    for (int i = 0; i < 8; ++i) {
        unsigned short h, l;
        tsplit(xv[i], h, l);
        hv[i] = (short)h; lv[i] = (short)l;
    }
}

// signed block-matrix element: Wg[kp][ap], Ug -> U[g][0][0][0]
__device__ inline float wElem(const float* __restrict__ Ug, int kp, int ap) {
    const int co = kp >> 7, ci = ap >> 7;
    const float v = Ug[((co == ci) ? 16384 : 0) + (kp & 127) * 128 + (ap & 127)];
    return (co & ci) ? -v : v;
}

// frag-linear scatter offset (in shorts) for element (row i, col t) of a 256x256 W
__device__ inline int fragOff(int i, int t) {
    const int frag = (i >> 4) * 8 + (t >> 5);
    const int slot = (i & 15) + 16 * ((t >> 3) & 3);
    return frag * 512 + slot * 8 + (t & 7);
}

// ---- prep 1: T = W1*W0 (fp32), assembling both from U inline ----
__global__ __launch_bounds__(256)
void prep_T(const float* __restrict__ U, float* __restrict__ T) {
    __shared__ float Arow[256];
    const int i = blockIdx.x, t = threadIdx.x;
    Arow[t] = wElem(U + 32768, i, t);               // W1 row i
    __syncthreads();
    float s = 0.f;
    #pragma unroll 8
    for (int k = 0; k < 256; ++k)
        s = fmaf(Arow[k], wElem(U, k, t), s);       // W0[k][t]
    T[i * 256 + t] = s;
}

// ---- prep 2: WA = W2*T, split + scatter to frag layout ----
__global__ __launch_bounds__(256)
void prep_WA(const float* __restrict__ U, const float* __restrict__ T,
             unsigned short* __restrict__ Wh, unsigned short* __restrict__ Wl) {
    __shared__ float Arow[256];
    const int i = blockIdx.x, t = threadIdx.x;
    Arow[t] = wElem(U + 2 * 32768, i, t);           // W2 row i
    __syncthreads();
    float s = 0.f;
    #pragma unroll 8
    for (int k = 0; k < 256; ++k)
        s = fmaf(Arow[k], T[k * 256 + t], s);
    unsigned short h, l;
    rsplit(s, h, l);
    const int off = fragOff(i, t);
    Wh[off] = h; Wl[off] = l;
}

// ---- prep 3: WB = W3 assembled, split + scatter ----
__global__ __launch_bounds__(256)
void prep_WB(const float* __restrict__ U,
             unsigned short* __restrict__ Wh, unsigned short* __restrict__ Wl) {
    const int i = blockIdx.x, t = threadIdx.x;
    unsigned short h, l;
    rsplit(wElem(U + 3 * 32768, i, t), h, l);
    const int off = fragOff(i, t);
    Wh[off] = h; Wl[off] = l;
}

// ---- fused main: 1024 blocks (512 h x 2 ka-halves) x 512 threads (8 waves) ----
__global__ __launch_bounds__(512, 4)
void fused2(const float* __restrict__ src, float* __restrict__ dst,
            const unsigned short* __restrict__ WAh, const unsigned short* __restrict__ WAl,
            const unsigned short* __restrict__ WBh, const unsigned short* __restrict__ WBl)
{
    __shared__ unsigned short Mh[32 * 512];   // 32 frags x 64 slots x 8 shorts = 32 KB
    __shared__ unsigned short Ml[32 * 512];

    const int t    = threadIdx.x;
    const int lane = t & 63;
    const int w    = t >> 6;            // 0..7
    const int col  = lane & 15, quad = lane >> 4;
    const int hidx = blockIdx.x >> 1;
    const int ka0  = (blockIdx.x & 1) * 64;
    const size_t hbase = (size_t)hidx * 16384;

    // ================= PASS A =================
    // m = b (8 tiles); wave: mh = w&1 -> 4 m-tiles. n = kp (block's 128, 8 tiles);
    // wave: nq = w>>1 -> 2 n-tiles (ktile = nq*2 + l2).
    const int mh = w & 1;
    const int nq = w >> 1;

    f32x4 acc[4][2];
    #pragma unroll
    for (int mi = 0; mi < 4; ++mi)
        #pragma unroll
        for (int l2 = 0; l2 < 2; ++l2) acc[mi][l2] = (f32x4)0.f;

    #pragma unroll 2
    for (int ks = 0; ks < 8; ++ks) {
        const int ch = ks >> 2;
        const int a  = (ks & 3) * 32 + quad * 8;
        const float* pa = src + (size_t)ch * NSTATE + hbase + a;
        bf16x8 ah[4], al[4];
        #pragma unroll
        for (int mi = 0; mi < 4; ++mi) {
            const int b = (mh * 4 + mi) * 16 + col;
            const float* p = pa + (size_t)b * 128;
            float xv[8];
            *(float4*)&xv[0] = *(const float4*)p;
            *(float4*)&xv[4] = *(const float4*)(p + 4);
            split8(xv, ah[mi], al[mi]);
        }
        #pragma unroll
        for (int l2 = 0; l2 < 2; ++l2) {
            const int ktile = nq * 2 + l2;
            const int wtile = (ktile >> 2) * 8 + (ka0 >> 4) + (ktile & 3);
            const int fo    = (wtile * 8 + ks) * 512 + lane * 8;
            bf16x8 bh = *(const bf16x8*)(WAh + fo);
            bf16x8 bl = *(const bf16x8*)(WAl + fo);
            #pragma unroll
            for (int mi = 0; mi < 4; ++mi) {
                acc[mi][l2] = __builtin_amdgcn_mfma_f32_16x16x32_bf16(ah[mi], bh, acc[mi][l2], 0, 0, 0);
                acc[mi][l2] = __builtin_amdgcn_mfma_f32_16x16x32_bf16(al[mi], bh, acc[mi][l2], 0, 0, 0);
                acc[mi][l2] = __builtin_amdgcn_mfma_f32_16x16x32_bf16(ah[mi], bl, acc[mi][l2], 0, 0, 0);
            }
        }
    }

    // ---- write MID pre-split to LDS frag layout ----
    // element (b = mtil*16 + quad*4 + r, kp -> T_ka = ktile&3, ch' = ktile>>2)
    // frag2 = T_ka*8 + ch'*4 + (mtil>>1); slot = col + 16*((mtil*2 + (quad>>1))&3);
    // short-offset within slot = (quad&1)*4 + r
    #pragma unroll
    for (int mi = 0; mi < 4; ++mi) {
        const int mtil = mh * 4 + mi;
        const int oct  = (mtil * 2 + (quad >> 1)) & 3;
        #pragma unroll
        for (int l2 = 0; l2 < 2; ++l2) {
            const int ktile = nq * 2 + l2;
            const int frag2 = (ktile & 3) * 8 + (ktile >> 2) * 4 + (mtil >> 1);
            const int soff  = frag2 * 512 + (col + 16 * oct) * 8 + (quad & 1) * 4;
            unsigned short hh[4], ll[4];
            #pragma unroll
            for (int r = 0; r < 4; ++r) tsplit(acc[mi][l2][r], hh[r], ll[r]);
            bf16x4 hv = { (short)hh[0], (short)hh[1], (short)hh[2], (short)hh[3] };
            bf16x4 lv = { (short)ll[0], (short)ll[1], (short)ll[2], (short)ll[3] };
            *(bf16x4*)&Mh[soff] = hv;
            *(bf16x4*)&Ml[soff] = lv;
        }
    }
    __syncthreads();    // the ONLY barrier

    // ================= PASS B =================
    // m2 = ka_loc (4 tiles); wave: mh2 = w&1 -> 2 tiles. n2 = kp2 (16 tiles);
    // wave: nq2 = w>>1 -> 4 tiles.
    const int mh2 = w & 1;
    const int nq2 = w >> 1;

    f32x4 acc2[2][4];
    #pragma unroll
    for (int mi = 0; mi < 2; ++mi)
        #pragma unroll
        for (int nj = 0; nj < 4; ++nj) acc2[mi][nj] = (f32x4)0.f;

    #pragma unroll 2
    for (int ks2 = 0; ks2 < 8; ++ks2) {
        bf16x8 a2h[2], a2l[2];
        #pragma unroll
        for (int mi = 0; mi < 2; ++mi) {
            const int fo = ((mh2 * 2 + mi) * 8 + ks2) * 512 + lane * 8;
            a2h[mi] = *(const bf16x8*)&Mh[fo];
            a2l[mi] = *(const bf16x8*)&Ml[fo];
        }
        #pragma unroll
        for (int nj = 0; nj < 4; ++nj) {
            const int nt = nq2 * 4 + nj;
            const int fo = (nt * 8 + ks2) * 512 + lane * 8;
            bf16x8 bh = *(const bf16x8*)(WBh + fo);
            bf16x8 bl = *(const bf16x8*)(WBl + fo);
            #pragma unroll
            for (int mi = 0; mi < 2; ++mi) {
                acc2[mi][nj] = __builtin_amdgcn_mfma_f32_16x16x32_bf16(a2h[mi], bh, acc2[mi][nj], 0, 0, 0);
                acc2[mi][nj] = __builtin_amdgcn_mfma_f32_16x16x32_bf16(a2l[mi], bh, acc2[mi][nj], 0, 0, 0);
                acc2[mi][nj] = __builtin_amdgcn_mfma_f32_16x16x32_bf16(a2h[mi], bl, acc2[mi][nj], 0, 0, 0);
            }
        }
    }

    // ---- epilogue: out[ch''][kb][ka0 + ka_loc], float4 over ka (coalesced) ----
    #pragma unroll
    for (int nj = 0; nj < 4; ++nj) {
        const int kp2  = (nq2 * 4 + nj) * 16 + col;
        const int chpp = kp2 >> 7, kb = kp2 & 127;
        float* o = dst + (size_t)chpp * NSTATE + hbase + (size_t)kb * 128 + ka0;
        #pragma unroll
        for (int mi = 0; mi < 2; ++mi) {
            const int ka_loc = (mh2 * 2 + mi) * 16 + quad * 4;
            *(float4*)(o + ka_loc) = *(float4*)&acc2[mi][nj];
        }
    }
}

extern "C" void kernel_launch(void* const* d_in, const int* in_sizes, int n_in,
                              void* d_out, int out_size, void* d_ws, size_t ws_size,
                              hipStream_t stream) {
    const float* state = (const float*)d_in[0];   // (2, 2^23)
    const float* U     = (const float*)d_in[1];   // (4, 2, 128, 128)
    float* out = (float*)d_out;

    // ws: T (256 KB fp32) | WAh WAl WBh WBl (128 KB each, frag-linear bf16)
    float* T = (float*)d_ws;
    unsigned short* WAh = (unsigned short*)(T + 65536);
    unsigned short* WAl = WAh + 65536;
    unsigned short* WBh = WAh + 2 * 65536;
    unsigned short* WBl = WAh + 3 * 65536;

    prep_T <<<256, 256, 0, stream>>>(U, T);
    prep_WA<<<256, 256, 0, stream>>>(U, T, WAh, WAl);
    prep_WB<<<256, 256, 0, stream>>>(U, WBh, WBl);
    fused2 <<<1024, 512, 0, stream>>>(state, out, WAh, WAl, WBh, WBl);
}